// Round 4
// baseline (8963.306 us; speedup 1.0000x reference)
//
#include <hip/hip_runtime.h>
#include <cstdint>

// ---------------------------------------------------------------------------
// BiLSTM-CRF on MI355X.
// Sizes: V=100000 E=300 H=256 S=4096 L=32 NC=64 CE=25 CO=25 T=12 START=10 STOP=11
// Output: f32[1] = forward_score - gold_score
//
// k_lstm (round 4): 256 threads/block, 1 block/direction, 1 wave/SIMD.
// Thread t owns all 4 gate rows of cell t. Whh row (128 f16 pairs) tiers:
//   pairs 0..35   LDS   (36 pairs, 144 KB/CU, DS pipe — free under VALU bound)
//   pairs 36..79  VGPR  (44 pairs, 176 VGPRs)
//   pairs 80..127 AGPR  (48 pairs, 192 AGPRs, non-volatile asm moves)
// h double-buffered f16 in LDS, depth-2 rolling prefetch, 1 barrier/step.
// ---------------------------------------------------------------------------

#define S_LEN 4096
#define EMB_LD 328            // embeds row stride (325 padded to 16B multiple)

typedef _Float16 half2_t __attribute__((ext_vector_type(2)));

__device__ __forceinline__ float fdot2(unsigned int a, unsigned int b, float acc) {
#if __has_builtin(__builtin_amdgcn_fdot2)
    return __builtin_amdgcn_fdot2(__builtin_bit_cast(half2_t, a),
                                  __builtin_bit_cast(half2_t, b), acc, false);
#else
    half2_t x = __builtin_bit_cast(half2_t, a);
    half2_t y = __builtin_bit_cast(half2_t, b);
    return acc + (float)x[0]*(float)y[0] + (float)x[1]*(float)y[1];
#endif
}

__device__ __forceinline__ unsigned int pack2f16(float a, float b) {
    union { _Float16 h[2]; unsigned int u; } v;
    v.h[0] = (_Float16)a; v.h[1] = (_Float16)b; return v.u;
}

__device__ __forceinline__ float sigm(float x) { return 1.0f / (1.0f + __expf(-x)); }

__device__ __forceinline__ float ftanh(float x) {
    float ax = fabsf(x);
    float e = __expf(-2.0f * ax);          // in (0,1], no overflow
    float t = (1.0f - e) / (1.0f + e);
    return copysignf(t, x);
}

// ---------------------------------------------------------------------------
// Workspace layout (bytes, all 256-aligned)
// ---------------------------------------------------------------------------
static constexpr size_t WS_EMBEDS = 0;                                // f32[4096][328]
static constexpr size_t WS_GI     = WS_EMBEDS + (size_t)4096*328*4;   // f32[2][4096][1024] ([s][cell][gate])
static constexpr size_t WS_WL     = WS_GI     + (size_t)2*4096*1024*4;// uint4[2][9][1024]
static constexpr size_t WS_WV     = WS_WL     + (size_t)2*9*1024*16;  // u32[2][44][1024]
static constexpr size_t WS_WA     = WS_WV     + (size_t)2*44*1024*4;  // u32[2][48][1024]
static constexpr size_t WS_CFEAT  = WS_WA     + (size_t)2*48*1024*4;  // f32[4096][25]
static constexpr size_t WS_HS     = WS_CFEAT  + (size_t)4096*25*4;    // f32[2][4096][256]
static constexpr size_t WS_FEATS  = WS_HS     + (size_t)2*4096*256*4; // f32[4096][12]
static constexpr size_t WS_CHUNKS = WS_FEATS  + (size_t)4096*12*4;    // f32[256][144]
static constexpr size_t WS_LVL2   = WS_CHUNKS + (size_t)256*144*4;    // f32[16][144]
static constexpr size_t WS_SCAL   = WS_LVL2   + (size_t)16*144*4;     // f32 scalars

// ---------------------------------------------------------------------------
// K1: pack Whh (fwd+bwd) to f16 in three tiers.
// elements 0..71    -> wl[dir][q][row] uint4, q=0..8   (LDS tier)
// elements 72..159  -> wv[dir][kp][row],     kp=0..43  (VGPR tier)
// elements 160..255 -> wa[dir][kp][row],     kp=0..47  (AGPR tier)
// ---------------------------------------------------------------------------
__global__ void k_pack(const float* __restrict__ whhf, const float* __restrict__ whhb,
                       uint4* __restrict__ wl, unsigned int* __restrict__ wv,
                       unsigned int* __restrict__ wa) {
    int idx = blockIdx.x * 256 + threadIdx.x;           // 0..2047
    if (idx >= 2048) return;
    int dir = idx >> 10, row = idx & 1023;
    const float* W = (dir ? whhb : whhf) + row * 256;
    uint4* wlp = wl + (size_t)dir * 9 * 1024;
    for (int q = 0; q < 9; q++) {
        int e0 = 8 * q;
        uint4 v;
        v.x = pack2f16(W[e0+0], W[e0+1]);
        v.y = pack2f16(W[e0+2], W[e0+3]);
        v.z = pack2f16(W[e0+4], W[e0+5]);
        v.w = pack2f16(W[e0+6], W[e0+7]);
        wlp[q * 1024 + row] = v;
    }
    unsigned int* wvp = wv + (size_t)dir * 44 * 1024;
    #pragma unroll 4
    for (int kp = 0; kp < 44; kp++)
        wvp[kp * 1024 + row] = pack2f16(W[72 + 2*kp], W[73 + 2*kp]);
    unsigned int* wap = wa + (size_t)dir * 48 * 1024;
    #pragma unroll 4
    for (int kp = 0; kp < 48; kp++)
        wap[kp * 1024 + row] = pack2f16(W[160 + 2*kp], W[161 + 2*kp]);
}

// ---------------------------------------------------------------------------
// K2: char CNN  (one block per word)
// ---------------------------------------------------------------------------
__global__ void k_charcnn(const int* __restrict__ chars, const float* __restrict__ cemb,
                          const float* __restrict__ convw, const float* __restrict__ convb,
                          float* __restrict__ cfeat) {
    int s = blockIdx.x, tid = threadIdx.x;              // 128 threads
    __shared__ float ce[32][25];
    __shared__ float wz[1875];                          // [25][3][25]
    __shared__ float bias[25];
    __shared__ float conv[850];                         // [34][25]
    for (int i = tid; i < 800; i += 128)
        ce[i / 25][i % 25] = cemb[chars[s * 32 + i / 25] * 25 + (i % 25)];
    for (int i = tid; i < 1875; i += 128) wz[i] = convw[i];
    if (tid < 25) bias[tid] = convb[tid];
    __syncthreads();
    for (int p = tid; p < 850; p += 128) {
        int tt = p / 25, o = p % 25;
        float acc = 0.f;
        #pragma unroll
        for (int kh = 0; kh < 3; kh++) {
            int tr = tt - 2 + kh;
            if (tr >= 0 && tr < 32) {
                const float* wrow = &wz[o * 75 + kh * 25];
                #pragma unroll
                for (int kw = 0; kw < 25; kw++) acc += ce[tr][kw] * wrow[kw];
            }
        }
        conv[p] = acc;
    }
    __syncthreads();
    if (tid < 25) {
        float m = conv[tid];
        for (int tt = 1; tt < 34; tt++) m = fmaxf(m, conv[tt * 25 + tid]);
        cfeat[s * 25 + tid] = m + bias[tid];
    }
}

// ---------------------------------------------------------------------------
// K3: embeds[s] = [ word_embed[sentence[s]] (300) | cfeat[s] (25) ]  stride 328
// ---------------------------------------------------------------------------
__global__ void k_embeds(const int* __restrict__ sentence, const float* __restrict__ wemb,
                         const float* __restrict__ cfeat, float* __restrict__ embeds) {
    int s = blockIdx.x, tid = threadIdx.x;              // 128 threads
    const float4* src = (const float4*)(wemb + (size_t)sentence[s] * 300);
    float4* dst = (float4*)(embeds + (size_t)s * EMB_LD);
    for (int i = tid; i < 75; i += 128) dst[i] = src[i];
    if (tid < 25) embeds[(size_t)s * EMB_LD + 300 + tid] = cfeat[s * 25 + tid];
    if (tid >= 25 && tid < 28) embeds[(size_t)s * EMB_LD + 325 + (tid - 25)] = 0.f; // pad
}

// ---------------------------------------------------------------------------
// K4: GEMM  gi = embeds @ Wih^T + b, output layout [dir][s][cell][gate]
// ---------------------------------------------------------------------------
__global__ __launch_bounds__(256) void k_gemm(const float* __restrict__ A,
        const float* __restrict__ Bf, const float* __restrict__ Bb,
        const float* __restrict__ bf, const float* __restrict__ bb,
        float* __restrict__ gi) {
    int bs = blockIdx.x;            // s-tile  [0,64)
    int br = blockIdx.y;            // row-tile [0,32)
    int dir = br >> 4;
    int row0 = (br & 15) * 64;
    const float* B = dir ? Bb : Bf;
    const float* bias = dir ? bb : bf;
    __shared__ float As[16][65], Bs[16][65];
    int tid = threadIdx.x;
    int tx = tid & 15, ty = tid >> 4;
    int s0 = bs * 64;
    float acc[4][4] = {};
    int lr = tid >> 2, lc0 = (tid & 3) * 4;
    for (int k0 = 0; k0 < 325; k0 += 16) {
        #pragma unroll
        for (int i = 0; i < 4; i++) {
            int k = k0 + lc0 + i;
            As[lc0 + i][lr] = (k < 325) ? A[(size_t)(s0 + lr) * EMB_LD + k] : 0.f;
            Bs[lc0 + i][lr] = (k < 325) ? B[(size_t)(row0 + lr) * 325 + k] : 0.f;
        }
        __syncthreads();
        #pragma unroll
        for (int kk = 0; kk < 16; kk++) {
            float a[4], b[4];
            #pragma unroll
            for (int i = 0; i < 4; i++) a[i] = As[kk][ty * 4 + i];
            #pragma unroll
            for (int j = 0; j < 4; j++) b[j] = Bs[kk][tx * 4 + j];
            #pragma unroll
            for (int i = 0; i < 4; i++)
                #pragma unroll
                for (int j = 0; j < 4; j++) acc[i][j] += a[i] * b[j];
        }
        __syncthreads();
    }
    #pragma unroll
    for (int i = 0; i < 4; i++)
        #pragma unroll
        for (int j = 0; j < 4; j++) {
            int row = row0 + tx * 4 + j;                 // 0..1023 = gate*256+cell
            int s   = s0 + ty * 4 + i;
            gi[(size_t)dir * 4194304 + (size_t)s * 1024 + (row & 255) * 4 + (row >> 8)]
                = acc[i][j] + bias[row];
        }
}

// ---------------------------------------------------------------------------
// K5: recurrence. grid=2 (direction), 256 threads, 1 wave/SIMD.
// ---------------------------------------------------------------------------
#define LSTM_LDS_BYTES (147456 + 1024)

__global__ __launch_bounds__(256, 1)
__attribute__((amdgpu_waves_per_eu(1, 1)))
void k_lstm(const uint4* __restrict__ wl, const unsigned int* __restrict__ wv,
            const unsigned int* __restrict__ wa, const float* __restrict__ gi,
            float* __restrict__ hs) {
    const int dir = blockIdx.x;
    const int t = threadIdx.x;                          // cell index 0..255
    extern __shared__ char smem[];
    uint4* tl          = (uint4*)smem;                  // [9][1024] LDS-tier weights
    unsigned int* hbuf = (unsigned int*)(smem + 147456);// 2 buffers x 128 f16-pairs

    // ---- VGPR-tier weights: wvr[g][kp], 176 u32 (pairs 36..79) ----
    unsigned int wvr[4][44];
    const unsigned int* wvb = wv + (size_t)dir * (44 * 1024);
    #pragma unroll
    for (int kp = 0; kp < 44; kp++)
        #pragma unroll
        for (int g = 0; g < 4; g++)
            wvr[g][kp] = wvb[kp * 1024 + g * 256 + t];

    // ---- AGPR-tier weights: areg[g][kp], 192 u32 in AGPRs (pairs 80..127) ----
    unsigned int areg[4][48];
    {
        const unsigned int* wab = wa + (size_t)dir * (48 * 1024);
        #pragma unroll
        for (int kp = 0; kp < 48; kp++)
            #pragma unroll
            for (int g = 0; g < 4; g++) {
                unsigned int v = wab[kp * 1024 + g * 256 + t];
                asm("v_accvgpr_write_b32 %0, %1" : "=a"(areg[g][kp]) : "v"(v));
            }
    }

    // ---- LDS-tier weights (pairs 0..35) ----
    {
        const uint4* wlb = wl + (size_t)dir * (9 * 1024);
        for (int i = t; i < 9216; i += 256) tl[i] = wlb[i];
    }
    hbuf[t] = 0u;                                       // zero both h buffers
    __syncthreads();

    const float* gib = gi + (size_t)dir * 4194304;
    float* hsb = hs + (size_t)dir * 1048576;
    const bool fw = (dir == 0);
    float c = 0.f;
    int sq0 = fw ? 0 : (S_LEN - 1);
    float4 gpre = *(const float4*)(gib + (size_t)sq0 * 1024 + t * 4);

    #pragma clang loop unroll(disable)
    for (int s = 0; s < S_LEN; s++) {
        int sq  = fw ? s : (S_LEN - 1 - s);
        int sn  = (s < S_LEN - 1) ? s + 1 : s;
        int sqn = fw ? sn : (S_LEN - 1 - sn);
        float acc[4] = { gpre.x, gpre.y, gpre.z, gpre.w };
        gpre = *(const float4*)(gib + (size_t)sqn * 1024 + t * 4);   // prefetch

        const uint4* hq = (const uint4*)(hbuf + (s & 1) * 128);
        uint4 h_a = hq[0];                               // depth-2 rolling prefetch
        uint4 h_b = hq[1];

        #pragma unroll
        for (int m = 0; m < 32; m++) {
            uint4 h4 = h_a;
            h_a = h_b;
            if (m < 30) h_b = hq[m + 2];

            if (m < 9) {
                // --- LDS tier: pairs 4m..4m+3 ---
                uint4 wq0 = tl[m * 1024 +           t];
                uint4 wq1 = tl[m * 1024 + 256     + t];
                uint4 wq2 = tl[m * 1024 + 512     + t];
                uint4 wq3 = tl[m * 1024 + 768     + t];
                acc[0] = fdot2(wq0.x, h4.x, acc[0]); acc[0] = fdot2(wq0.y, h4.y, acc[0]);
                acc[0] = fdot2(wq0.z, h4.z, acc[0]); acc[0] = fdot2(wq0.w, h4.w, acc[0]);
                acc[1] = fdot2(wq1.x, h4.x, acc[1]); acc[1] = fdot2(wq1.y, h4.y, acc[1]);
                acc[1] = fdot2(wq1.z, h4.z, acc[1]); acc[1] = fdot2(wq1.w, h4.w, acc[1]);
                acc[2] = fdot2(wq2.x, h4.x, acc[2]); acc[2] = fdot2(wq2.y, h4.y, acc[2]);
                acc[2] = fdot2(wq2.z, h4.z, acc[2]); acc[2] = fdot2(wq2.w, h4.w, acc[2]);
                acc[3] = fdot2(wq3.x, h4.x, acc[3]); acc[3] = fdot2(wq3.y, h4.y, acc[3]);
                acc[3] = fdot2(wq3.z, h4.z, acc[3]); acc[3] = fdot2(wq3.w, h4.w, acc[3]);
            } else if (m < 20) {
                // --- VGPR tier: tier pair kp = 4*(m-9)+j ---
                int kp0 = 4 * (m - 9);
                #pragma unroll
                for (int g = 0; g < 4; g++) {
                    acc[g] = fdot2(wvr[g][kp0+0], h4.x, acc[g]);
                    acc[g] = fdot2(wvr[g][kp0+1], h4.y, acc[g]);
                    acc[g] = fdot2(wvr[g][kp0+2], h4.z, acc[g]);
                    acc[g] = fdot2(wvr[g][kp0+3], h4.w, acc[g]);
                }
            } else {
                // --- AGPR tier: tier pair kp = 4*(m-20)+j ---
                int kp0 = 4 * (m - 20);
                unsigned int hh[4] = { h4.x, h4.y, h4.z, h4.w };
                #pragma unroll
                for (int j = 0; j < 4; j++) {
                    unsigned int wt0, wt1, wt2, wt3;
                    asm("v_accvgpr_read_b32 %0, %1" : "=v"(wt0) : "a"(areg[0][kp0+j]));
                    asm("v_accvgpr_read_b32 %0, %1" : "=v"(wt1) : "a"(areg[1][kp0+j]));
                    asm("v_accvgpr_read_b32 %0, %1" : "=v"(wt2) : "a"(areg[2][kp0+j]));
                    asm("v_accvgpr_read_b32 %0, %1" : "=v"(wt3) : "a"(areg[3][kp0+j]));
                    acc[0] = fdot2(wt0, hh[j], acc[0]);
                    acc[1] = fdot2(wt1, hh[j], acc[1]);
                    acc[2] = fdot2(wt2, hh[j], acc[2]);
                    acc[3] = fdot2(wt3, hh[j], acc[3]);
                }
            }
        }

        // all four gates local: acc = {i, f, g, o}
        float ig = sigm(acc[0]);
        float fg = sigm(acc[1]);
        float gg = ftanh(acc[2]);
        float og = sigm(acc[3]);
        c = fg * c + ig * gg;
        float h = og * ftanh(c);
        hsb[(size_t)sq * 256 + t] = h;
        unsigned short* hp16 = (unsigned short*)(hbuf + ((s + 1) & 1) * 128);
        union { _Float16 hh; unsigned short u; } cv; cv.hh = (_Float16)h;
        hp16[t] = cv.u;
        __syncthreads();                                 // publish next h buffer
    }
}

// ---------------------------------------------------------------------------
// K6: feats[s][j] = b_tag[j] + hs_f[s]·W_tag[j][0:256] + hs_b[s]·W_tag[j][256:512]
// 192 threads: j = tid/16, 16 lanes per j, shfl reduce.
// ---------------------------------------------------------------------------
__global__ void k_feats(const float* __restrict__ hs, const float* __restrict__ wtag,
                        const float* __restrict__ btag, float* __restrict__ feats) {
    int s = blockIdx.x, tid = threadIdx.x;               // 192 threads
    int j = tid >> 4, l = tid & 15;
    const float* hf = hs + (size_t)s * 256;
    const float* hb = hs + 1048576 + (size_t)s * 256;
    const float* w = wtag + j * 512;
    float p = 0.f;
    int k0 = l * 16;
    #pragma unroll
    for (int k = 0; k < 16; k++) p += hf[k0 + k] * w[k0 + k];
    #pragma unroll
    for (int k = 0; k < 16; k++) p += hb[k0 + k] * w[256 + k0 + k];
    p += __shfl_down(p, 8, 16);
    p += __shfl_down(p, 4, 16);
    p += __shfl_down(p, 2, 16);
    p += __shfl_down(p, 1, 16);
    if (l == 0) feats[s * 12 + j] = btag[j] + p;
}

// ---------------------------------------------------------------------------
// K7: gold score (single block)
// ---------------------------------------------------------------------------
__global__ void k_gold(const float* __restrict__ feats, const int* __restrict__ tags,
                       const float* __restrict__ trans, float* __restrict__ scal) {
    __shared__ float red[256];
    int tid = threadIdx.x;
    float p = 0.f;
    for (int s = tid; s < S_LEN; s += 256) {
        int tg = tags[s];
        p += feats[s * 12 + tg];
        int prev = (s == 0) ? 10 : tags[s - 1];
        p += trans[prev * 12 + tg];
    }
    if (tid == 0) p += trans[tags[S_LEN - 1] * 12 + 11];
    red[tid] = p;
    __syncthreads();
    for (int off = 128; off; off >>= 1) {
        if (tid < off) red[tid] += red[tid + off];
        __syncthreads();
    }
    if (tid == 0) scal[0] = red[0];
}

// ---------------------------------------------------------------------------
// CRF as ordered log-matmul tree-reduction.  M_s[i][j] = trans[i][j] + feat[s][j].
// ---------------------------------------------------------------------------
__device__ __forceinline__ void lse_merge(const float* A, const float* B, float* C, int tid) {
    if (tid < 144) {
        int i = tid / 12, j = tid % 12;
        float m = -1e30f;
        #pragma unroll
        for (int k = 0; k < 12; k++) m = fmaxf(m, A[i * 12 + k] + B[k * 12 + j]);
        float sum = 0.f;
        #pragma unroll
        for (int k = 0; k < 12; k++) sum += __expf(A[i * 12 + k] + B[k * 12 + j] - m);
        C[tid] = m + __logf(sum);
    }
}

// K8: chunk products of 16 consecutive M_s (256 blocks)
__global__ void k_crf1(const float* __restrict__ feats, const float* __restrict__ trans,
                       float* __restrict__ chunks) {
    int b = blockIdx.x, tid = threadIdx.x;               // 192 threads, 144 active
    __shared__ float A[144], Bv[144], Tr[144];
    if (tid < 144) Tr[tid] = trans[tid];
    int s0 = b * 16;
    if (tid < 144) A[tid] = trans[tid] + feats[s0 * 12 + (tid % 12)];
    __syncthreads();
    float* cur = A; float* nxt = Bv;
    for (int s = s0 + 1; s < s0 + 16; s++) {
        if (tid < 144) {
            int i = tid / 12, j = tid % 12;
            float m = -1e30f;
            #pragma unroll
            for (int k = 0; k < 12; k++) m = fmaxf(m, cur[i * 12 + k] + Tr[k * 12 + j]);
            float sum = 0.f;
            #pragma unroll
            for (int k = 0; k < 12; k++) sum += __expf(cur[i * 12 + k] + Tr[k * 12 + j] - m);
            nxt[tid] = feats[s * 12 + j] + m + __logf(sum);
        }
        __syncthreads();
        float* tmp = cur; cur = nxt; nxt = tmp;
    }
    if (tid < 144) chunks[b * 144 + tid] = cur[tid];
}

// K9: fold 16 chunks each (16 blocks)
__global__ void k_crf2(const float* __restrict__ chunks, float* __restrict__ lvl2) {
    int b = blockIdx.x, tid = threadIdx.x;               // 192 threads
    __shared__ float A[144], Bv[144], Cc[144];
    if (tid < 144) A[tid] = chunks[(size_t)(b * 16) * 144 + tid];
    __syncthreads();
    for (int m2 = 1; m2 < 16; m2++) {
        if (tid < 144) Bv[tid] = chunks[(size_t)(b * 16 + m2) * 144 + tid];
        __syncthreads();
        lse_merge(A, Bv, Cc, tid);
        __syncthreads();
        if (tid < 144) A[tid] = Cc[tid];
        __syncthreads();
    }
    if (tid < 144) lvl2[b * 144 + tid] = A[tid];
}

// K10: final fold + score (1 block)
__global__ void k_crf3(const float* __restrict__ lvl2, const float* __restrict__ trans,
                       const float* __restrict__ scal, float* __restrict__ out) {
    __shared__ float A[144], Bv[144], Cc[144], alpha[12];
    int tid = threadIdx.x;                               // 192 threads
    if (tid < 144) A[tid] = lvl2[tid];
    __syncthreads();
    for (int m2 = 1; m2 < 16; m2++) {
        if (tid < 144) Bv[tid] = lvl2[m2 * 144 + tid];
        __syncthreads();
        lse_merge(A, Bv, Cc, tid);
        __syncthreads();
        if (tid < 144) A[tid] = Cc[tid];
        __syncthreads();
    }
    if (tid < 12) {
        int j = tid;
        float m = -1e30f;
        #pragma unroll
        for (int i = 0; i < 12; i++) {
            float v = ((i == 10) ? 0.f : -10000.f) + A[i * 12 + j];
            m = fmaxf(m, v);
        }
        float sum = 0.f;
        #pragma unroll
        for (int i = 0; i < 12; i++) {
            float v = ((i == 10) ? 0.f : -10000.f) + A[i * 12 + j];
            sum += __expf(v - m);
        }
        alpha[j] = m + __logf(sum) + trans[j * 12 + 11];
    }
    __syncthreads();
    if (tid == 0) {
        float m = -1e30f;
        #pragma unroll
        for (int j = 0; j < 12; j++) m = fmaxf(m, alpha[j]);
        float sum = 0.f;
        #pragma unroll
        for (int j = 0; j < 12; j++) sum += __expf(alpha[j] - m);
        out[0] = (m + __logf(sum)) - scal[0];
    }
}

// ---------------------------------------------------------------------------
extern "C" void kernel_launch(void* const* d_in, const int* in_sizes, int n_in,
                              void* d_out, int out_size, void* d_ws, size_t ws_size,
                              hipStream_t stream) {
    const int*   sentence = (const int*)d_in[0];
    const int*   chars    = (const int*)d_in[1];
    const int*   tags     = (const int*)d_in[2];
    const float* wemb     = (const float*)d_in[4];
    const float* cemb     = (const float*)d_in[5];
    const float* convw    = (const float*)d_in[6];
    const float* convb    = (const float*)d_in[7];
    const float* wihf     = (const float*)d_in[8];
    const float* whhf     = (const float*)d_in[9];
    const float* bf       = (const float*)d_in[10];
    const float* wihb     = (const float*)d_in[11];
    const float* whhb     = (const float*)d_in[12];
    const float* bb       = (const float*)d_in[13];
    const float* wtag     = (const float*)d_in[14];
    const float* btag     = (const float*)d_in[15];
    const float* trans    = (const float*)d_in[16];

    char* ws = (char*)d_ws;
    float*        embeds = (float*)(ws + WS_EMBEDS);
    float*        gi     = (float*)(ws + WS_GI);
    uint4*        wl     = (uint4*)(ws + WS_WL);
    unsigned int* wv     = (unsigned int*)(ws + WS_WV);
    unsigned int* wa     = (unsigned int*)(ws + WS_WA);
    float*        cfeat  = (float*)(ws + WS_CFEAT);
    float*        hsbuf  = (float*)(ws + WS_HS);
    float*        feats  = (float*)(ws + WS_FEATS);
    float*        chunks = (float*)(ws + WS_CHUNKS);
    float*        lvl2   = (float*)(ws + WS_LVL2);
    float*        scal   = (float*)(ws + WS_SCAL);

    hipFuncSetAttribute((const void*)k_lstm,
                        hipFuncAttributeMaxDynamicSharedMemorySize, LSTM_LDS_BYTES);

    k_pack<<<8, 256, 0, stream>>>(whhf, whhb, wl, wv, wa);
    k_charcnn<<<4096, 128, 0, stream>>>(chars, cemb, convw, convb, cfeat);
    k_embeds<<<4096, 128, 0, stream>>>(sentence, wemb, cfeat, embeds);
    k_gemm<<<dim3(64, 32), 256, 0, stream>>>(embeds, wihf, wihb, bf, bb, gi);
    k_lstm<<<2, 256, LSTM_LDS_BYTES, stream>>>(wl, wv, wa, gi, hsbuf);
    k_feats<<<4096, 192, 0, stream>>>(hsbuf, wtag, btag, feats);
    k_gold<<<1, 256, 0, stream>>>(feats, tags, trans, scal);
    k_crf1<<<256, 192, 0, stream>>>(feats, trans, chunks);
    k_crf2<<<16, 192, 0, stream>>>(chunks, lvl2);
    k_crf3<<<1, 192, 0, stream>>>(lvl2, trans, scal, (float*)d_out);
}

// Round 5
// 8862.476 us; speedup vs baseline: 1.0114x; 1.0114x over previous
//
#include <hip/hip_runtime.h>
#include <cstdint>

// ---------------------------------------------------------------------------
// BiLSTM-CRF on MI355X.
// Sizes: V=100000 E=300 H=256 S=4096 L=32 NC=64 CE=25 CO=25 T=12 START=10 STOP=11
// Output: f32[1] = forward_score - gold_score
//
// k_lstm (round 5): 256 threads/block, 1 block/direction, 1 wave/SIMD.
// Thread t owns all 4 gate rows of cell t. Whh row (128 f16 pairs) tiers:
//   pairs 0..23   LDS   (24 pairs, 96 KB, double-buffered chunk prefetch)
//   pairs 24..67  VGPR  (44 pairs, 176 VGPRs)
//   pairs 68..127 AGPR  (60 pairs, 240 AGPRs, non-volatile asm moves)
// Cost model (R3/R4 A-B): LDS weight b128 ~12cy on shared DS pipe (expensive),
// AGPR read = 2cy on own SIMD (cheap), VGPR free. Minimize LDS tier.
// ---------------------------------------------------------------------------

#define S_LEN 4096
#define EMB_LD 328            // embeds row stride (325 padded to 16B multiple)

typedef _Float16 half2_t __attribute__((ext_vector_type(2)));

__device__ __forceinline__ float fdot2(unsigned int a, unsigned int b, float acc) {
#if __has_builtin(__builtin_amdgcn_fdot2)
    return __builtin_amdgcn_fdot2(__builtin_bit_cast(half2_t, a),
                                  __builtin_bit_cast(half2_t, b), acc, false);
#else
    half2_t x = __builtin_bit_cast(half2_t, a);
    half2_t y = __builtin_bit_cast(half2_t, b);
    return acc + (float)x[0]*(float)y[0] + (float)x[1]*(float)y[1];
#endif
}

__device__ __forceinline__ unsigned int pack2f16(float a, float b) {
    union { _Float16 h[2]; unsigned int u; } v;
    v.h[0] = (_Float16)a; v.h[1] = (_Float16)b; return v.u;
}

__device__ __forceinline__ float sigm(float x) { return 1.0f / (1.0f + __expf(-x)); }

__device__ __forceinline__ float ftanh(float x) {
    float ax = fabsf(x);
    float e = __expf(-2.0f * ax);          // in (0,1], no overflow
    float t = (1.0f - e) / (1.0f + e);
    return copysignf(t, x);
}

// ---------------------------------------------------------------------------
// Workspace layout (bytes, all 256-aligned)
// ---------------------------------------------------------------------------
static constexpr size_t WS_EMBEDS = 0;                                // f32[4096][328]
static constexpr size_t WS_GI     = WS_EMBEDS + (size_t)4096*328*4;   // f32[2][4096][1024] ([s][cell][gate])
static constexpr size_t WS_WL     = WS_GI     + (size_t)2*4096*1024*4;// uint4[2][6][1024]
static constexpr size_t WS_WV     = WS_WL     + (size_t)2*6*1024*16;  // u32[2][44][1024]
static constexpr size_t WS_WA     = WS_WV     + (size_t)2*44*1024*4;  // u32[2][60][1024]
static constexpr size_t WS_CFEAT  = WS_WA     + (size_t)2*60*1024*4;  // f32[4096][25]
static constexpr size_t WS_HS     = WS_CFEAT  + (size_t)4096*25*4;    // f32[2][4096][256]
static constexpr size_t WS_FEATS  = WS_HS     + (size_t)2*4096*256*4; // f32[4096][12]
static constexpr size_t WS_CHUNKS = WS_FEATS  + (size_t)4096*12*4;    // f32[256][144]
static constexpr size_t WS_LVL2   = WS_CHUNKS + (size_t)256*144*4;    // f32[16][144]
static constexpr size_t WS_SCAL   = WS_LVL2   + (size_t)16*144*4;     // f32 scalars

// ---------------------------------------------------------------------------
// K1: pack Whh (fwd+bwd) to f16 in three tiers.
// elements 0..47    -> wl[dir][q][row] uint4, q=0..5   (LDS tier,  pairs 0..23)
// elements 48..135  -> wv[dir][kp][row],     kp=0..43  (VGPR tier, pairs 24..67)
// elements 136..255 -> wa[dir][kp][row],     kp=0..59  (AGPR tier, pairs 68..127)
// ---------------------------------------------------------------------------
__global__ void k_pack(const float* __restrict__ whhf, const float* __restrict__ whhb,
                       uint4* __restrict__ wl, unsigned int* __restrict__ wv,
                       unsigned int* __restrict__ wa) {
    int idx = blockIdx.x * 256 + threadIdx.x;           // 0..2047
    if (idx >= 2048) return;
    int dir = idx >> 10, row = idx & 1023;
    const float* W = (dir ? whhb : whhf) + row * 256;
    uint4* wlp = wl + (size_t)dir * 6 * 1024;
    for (int q = 0; q < 6; q++) {
        int e0 = 8 * q;
        uint4 v;
        v.x = pack2f16(W[e0+0], W[e0+1]);
        v.y = pack2f16(W[e0+2], W[e0+3]);
        v.z = pack2f16(W[e0+4], W[e0+5]);
        v.w = pack2f16(W[e0+6], W[e0+7]);
        wlp[q * 1024 + row] = v;
    }
    unsigned int* wvp = wv + (size_t)dir * 44 * 1024;
    #pragma unroll 4
    for (int kp = 0; kp < 44; kp++)
        wvp[kp * 1024 + row] = pack2f16(W[48 + 2*kp], W[49 + 2*kp]);
    unsigned int* wap = wa + (size_t)dir * 60 * 1024;
    #pragma unroll 4
    for (int kp = 0; kp < 60; kp++)
        wap[kp * 1024 + row] = pack2f16(W[136 + 2*kp], W[137 + 2*kp]);
}

// ---------------------------------------------------------------------------
// K2: char CNN  (one block per word)
// ---------------------------------------------------------------------------
__global__ void k_charcnn(const int* __restrict__ chars, const float* __restrict__ cemb,
                          const float* __restrict__ convw, const float* __restrict__ convb,
                          float* __restrict__ cfeat) {
    int s = blockIdx.x, tid = threadIdx.x;              // 128 threads
    __shared__ float ce[32][25];
    __shared__ float wz[1875];                          // [25][3][25]
    __shared__ float bias[25];
    __shared__ float conv[850];                         // [34][25]
    for (int i = tid; i < 800; i += 128)
        ce[i / 25][i % 25] = cemb[chars[s * 32 + i / 25] * 25 + (i % 25)];
    for (int i = tid; i < 1875; i += 128) wz[i] = convw[i];
    if (tid < 25) bias[tid] = convb[tid];
    __syncthreads();
    for (int p = tid; p < 850; p += 128) {
        int tt = p / 25, o = p % 25;
        float acc = 0.f;
        #pragma unroll
        for (int kh = 0; kh < 3; kh++) {
            int tr = tt - 2 + kh;
            if (tr >= 0 && tr < 32) {
                const float* wrow = &wz[o * 75 + kh * 25];
                #pragma unroll
                for (int kw = 0; kw < 25; kw++) acc += ce[tr][kw] * wrow[kw];
            }
        }
        conv[p] = acc;
    }
    __syncthreads();
    if (tid < 25) {
        float m = conv[tid];
        for (int tt = 1; tt < 34; tt++) m = fmaxf(m, conv[tt * 25 + tid]);
        cfeat[s * 25 + tid] = m + bias[tid];
    }
}

// ---------------------------------------------------------------------------
// K3: embeds[s] = [ word_embed[sentence[s]] (300) | cfeat[s] (25) ]  stride 328
// ---------------------------------------------------------------------------
__global__ void k_embeds(const int* __restrict__ sentence, const float* __restrict__ wemb,
                         const float* __restrict__ cfeat, float* __restrict__ embeds) {
    int s = blockIdx.x, tid = threadIdx.x;              // 128 threads
    const float4* src = (const float4*)(wemb + (size_t)sentence[s] * 300);
    float4* dst = (float4*)(embeds + (size_t)s * EMB_LD);
    for (int i = tid; i < 75; i += 128) dst[i] = src[i];
    if (tid < 25) embeds[(size_t)s * EMB_LD + 300 + tid] = cfeat[s * 25 + tid];
    if (tid >= 25 && tid < 28) embeds[(size_t)s * EMB_LD + 325 + (tid - 25)] = 0.f; // pad
}

// ---------------------------------------------------------------------------
// K4: GEMM  gi = embeds @ Wih^T + b, output layout [dir][s][cell][gate]
// ---------------------------------------------------------------------------
__global__ __launch_bounds__(256) void k_gemm(const float* __restrict__ A,
        const float* __restrict__ Bf, const float* __restrict__ Bb,
        const float* __restrict__ bf, const float* __restrict__ bb,
        float* __restrict__ gi) {
    int bs = blockIdx.x;            // s-tile  [0,64)
    int br = blockIdx.y;            // row-tile [0,32)
    int dir = br >> 4;
    int row0 = (br & 15) * 64;
    const float* B = dir ? Bb : Bf;
    const float* bias = dir ? bb : bf;
    __shared__ float As[16][65], Bs[16][65];
    int tid = threadIdx.x;
    int tx = tid & 15, ty = tid >> 4;
    int s0 = bs * 64;
    float acc[4][4] = {};
    int lr = tid >> 2, lc0 = (tid & 3) * 4;
    for (int k0 = 0; k0 < 325; k0 += 16) {
        #pragma unroll
        for (int i = 0; i < 4; i++) {
            int k = k0 + lc0 + i;
            As[lc0 + i][lr] = (k < 325) ? A[(size_t)(s0 + lr) * EMB_LD + k] : 0.f;
            Bs[lc0 + i][lr] = (k < 325) ? B[(size_t)(row0 + lr) * 325 + k] : 0.f;
        }
        __syncthreads();
        #pragma unroll
        for (int kk = 0; kk < 16; kk++) {
            float a[4], b[4];
            #pragma unroll
            for (int i = 0; i < 4; i++) a[i] = As[kk][ty * 4 + i];
            #pragma unroll
            for (int j = 0; j < 4; j++) b[j] = Bs[kk][tx * 4 + j];
            #pragma unroll
            for (int i = 0; i < 4; i++)
                #pragma unroll
                for (int j = 0; j < 4; j++) acc[i][j] += a[i] * b[j];
        }
        __syncthreads();
    }
    #pragma unroll
    for (int i = 0; i < 4; i++)
        #pragma unroll
        for (int j = 0; j < 4; j++) {
            int row = row0 + tx * 4 + j;                 // 0..1023 = gate*256+cell
            int s   = s0 + ty * 4 + i;
            gi[(size_t)dir * 4194304 + (size_t)s * 1024 + (row & 255) * 4 + (row >> 8)]
                = acc[i][j] + bias[row];
        }
}

// ---------------------------------------------------------------------------
// K5: recurrence. grid=2 (direction), 256 threads, 1 wave/SIMD.
// ---------------------------------------------------------------------------
#define LSTM_LDS_BYTES (98304 + 1024)

__global__ __launch_bounds__(256, 1)
__attribute__((amdgpu_waves_per_eu(1, 1)))
void k_lstm(const uint4* __restrict__ wl, const unsigned int* __restrict__ wv,
            const unsigned int* __restrict__ wa, const float* __restrict__ gi,
            float* __restrict__ hs) {
    const int dir = blockIdx.x;
    const int t = threadIdx.x;                          // cell index 0..255
    extern __shared__ char smem[];
    uint4* tl          = (uint4*)smem;                  // [6][1024] LDS-tier weights
    unsigned int* hbuf = (unsigned int*)(smem + 98304); // 2 buffers x 128 f16-pairs

    // ---- VGPR-tier weights: wvr[g][kp], 176 u32 (pairs 24..67) ----
    unsigned int wvr[4][44];
    const unsigned int* wvb = wv + (size_t)dir * (44 * 1024);
    #pragma unroll
    for (int kp = 0; kp < 44; kp++)
        #pragma unroll
        for (int g = 0; g < 4; g++)
            wvr[g][kp] = wvb[kp * 1024 + g * 256 + t];

    // ---- AGPR-tier weights: areg[g][kp], 240 u32 in AGPRs (pairs 68..127) ----
    unsigned int areg[4][60];
    {
        const unsigned int* wab = wa + (size_t)dir * (60 * 1024);
        #pragma unroll
        for (int kp = 0; kp < 60; kp++)
            #pragma unroll
            for (int g = 0; g < 4; g++) {
                unsigned int v = wab[kp * 1024 + g * 256 + t];
                asm("v_accvgpr_write_b32 %0, %1" : "=a"(areg[g][kp]) : "v"(v));
            }
    }

    // ---- LDS-tier weights (pairs 0..23) ----
    {
        const uint4* wlb = wl + (size_t)dir * (6 * 1024);
        for (int i = t; i < 6144; i += 256) tl[i] = wlb[i];
    }
    hbuf[t] = 0u;                                       // zero both h buffers
    __syncthreads();

    const float* gib = gi + (size_t)dir * 4194304;
    float* hsb = hs + (size_t)dir * 1048576;
    const bool fw = (dir == 0);
    float c = 0.f;
    int sq0 = fw ? 0 : (S_LEN - 1);
    float4 gpre = *(const float4*)(gib + (size_t)sq0 * 1024 + t * 4);

    #pragma clang loop unroll(disable)
    for (int s = 0; s < S_LEN; s++) {
        int sq  = fw ? s : (S_LEN - 1 - s);
        int sn  = (s < S_LEN - 1) ? s + 1 : s;
        int sqn = fw ? sn : (S_LEN - 1 - sn);
        float acc[4] = { gpre.x, gpre.y, gpre.z, gpre.w };
        gpre = *(const float4*)(gib + (size_t)sqn * 1024 + t * 4);   // prefetch

        const uint4* hq = (const uint4*)(hbuf + (s & 1) * 128);

        // preload LDS weight chunk 0 + first two h chunks
        uint4 wbuf[2][4];
        #pragma unroll
        for (int g = 0; g < 4; g++) wbuf[0][g] = tl[g * 256 + t];
        uint4 h_a = hq[0];
        uint4 h_b = hq[1];

        // --- Phase L: LDS tier, m = 0..5 (pairs 0..23), rolling prefetch ---
        #pragma unroll
        for (int m = 0; m < 6; m++) {
            uint4 h4 = h_a;
            h_a = h_b;
            h_b = hq[m + 2];
            if (m < 5) {                                 // prefetch next chunk
                #pragma unroll
                for (int g = 0; g < 4; g++)
                    wbuf[(m + 1) & 1][g] = tl[(m + 1) * 1024 + g * 256 + t];
            }
            #pragma unroll
            for (int g = 0; g < 4; g++) {
                uint4 wq = wbuf[m & 1][g];
                acc[g] = fdot2(wq.x, h4.x, acc[g]);
                acc[g] = fdot2(wq.y, h4.y, acc[g]);
                acc[g] = fdot2(wq.z, h4.z, acc[g]);
                acc[g] = fdot2(wq.w, h4.w, acc[g]);
            }
        }
        // --- Phase V: VGPR tier, m = 6..16 (pairs 24..67) ---
        #pragma unroll
        for (int m = 6; m < 17; m++) {
            uint4 h4 = h_a;
            h_a = h_b;
            h_b = hq[m + 2];
            int kp0 = 4 * (m - 6);
            #pragma unroll
            for (int g = 0; g < 4; g++) {
                acc[g] = fdot2(wvr[g][kp0+0], h4.x, acc[g]);
                acc[g] = fdot2(wvr[g][kp0+1], h4.y, acc[g]);
                acc[g] = fdot2(wvr[g][kp0+2], h4.z, acc[g]);
                acc[g] = fdot2(wvr[g][kp0+3], h4.w, acc[g]);
            }
        }
        // --- Phase A: AGPR tier, m = 17..31 (pairs 68..127) ---
        #pragma unroll
        for (int m = 17; m < 32; m++) {
            uint4 h4 = h_a;
            h_a = h_b;
            if (m < 30) h_b = hq[m + 2];
            int kp0 = 4 * (m - 17);
            unsigned int hh[4] = { h4.x, h4.y, h4.z, h4.w };
            #pragma unroll
            for (int j = 0; j < 4; j++) {
                unsigned int wt0, wt1, wt2, wt3;
                asm("v_accvgpr_read_b32 %0, %1" : "=v"(wt0) : "a"(areg[0][kp0+j]));
                asm("v_accvgpr_read_b32 %0, %1" : "=v"(wt1) : "a"(areg[1][kp0+j]));
                asm("v_accvgpr_read_b32 %0, %1" : "=v"(wt2) : "a"(areg[2][kp0+j]));
                asm("v_accvgpr_read_b32 %0, %1" : "=v"(wt3) : "a"(areg[3][kp0+j]));
                acc[0] = fdot2(wt0, hh[j], acc[0]);
                acc[1] = fdot2(wt1, hh[j], acc[1]);
                acc[2] = fdot2(wt2, hh[j], acc[2]);
                acc[3] = fdot2(wt3, hh[j], acc[3]);
            }
        }

        // all four gates local: acc = {i, f, g, o}
        float ig = sigm(acc[0]);
        float fg = sigm(acc[1]);
        float gg = ftanh(acc[2]);
        float og = sigm(acc[3]);
        c = fg * c + ig * gg;
        float h = og * ftanh(c);
        unsigned short* hp16 = (unsigned short*)(hbuf + ((s + 1) & 1) * 128);
        union { _Float16 hh; unsigned short u; } cv; cv.hh = (_Float16)h;
        hp16[t] = cv.u;
        hsb[(size_t)sq * 256 + t] = h;
        __syncthreads();                                 // publish next h buffer
    }
}

// ---------------------------------------------------------------------------
// K6: feats[s][j] = b_tag[j] + hs_f[s]·W_tag[j][0:256] + hs_b[s]·W_tag[j][256:512]
// 192 threads: j = tid/16, 16 lanes per j, shfl reduce.
// ---------------------------------------------------------------------------
__global__ void k_feats(const float* __restrict__ hs, const float* __restrict__ wtag,
                        const float* __restrict__ btag, float* __restrict__ feats) {
    int s = blockIdx.x, tid = threadIdx.x;               // 192 threads
    int j = tid >> 4, l = tid & 15;
    const float* hf = hs + (size_t)s * 256;
    const float* hb = hs + 1048576 + (size_t)s * 256;
    const float* w = wtag + j * 512;
    float p = 0.f;
    int k0 = l * 16;
    #pragma unroll
    for (int k = 0; k < 16; k++) p += hf[k0 + k] * w[k0 + k];
    #pragma unroll
    for (int k = 0; k < 16; k++) p += hb[k0 + k] * w[256 + k0 + k];
    p += __shfl_down(p, 8, 16);
    p += __shfl_down(p, 4, 16);
    p += __shfl_down(p, 2, 16);
    p += __shfl_down(p, 1, 16);
    if (l == 0) feats[s * 12 + j] = btag[j] + p;
}

// ---------------------------------------------------------------------------
// K7: gold score (single block)
// ---------------------------------------------------------------------------
__global__ void k_gold(const float* __restrict__ feats, const int* __restrict__ tags,
                       const float* __restrict__ trans, float* __restrict__ scal) {
    __shared__ float red[256];
    int tid = threadIdx.x;
    float p = 0.f;
    for (int s = tid; s < S_LEN; s += 256) {
        int tg = tags[s];
        p += feats[s * 12 + tg];
        int prev = (s == 0) ? 10 : tags[s - 1];
        p += trans[prev * 12 + tg];
    }
    if (tid == 0) p += trans[tags[S_LEN - 1] * 12 + 11];
    red[tid] = p;
    __syncthreads();
    for (int off = 128; off; off >>= 1) {
        if (tid < off) red[tid] += red[tid + off];
        __syncthreads();
    }
    if (tid == 0) scal[0] = red[0];
}

// ---------------------------------------------------------------------------
// CRF as ordered log-matmul tree-reduction.  M_s[i][j] = trans[i][j] + feat[s][j].
// ---------------------------------------------------------------------------
__device__ __forceinline__ void lse_merge(const float* A, const float* B, float* C, int tid) {
    if (tid < 144) {
        int i = tid / 12, j = tid % 12;
        float m = -1e30f;
        #pragma unroll
        for (int k = 0; k < 12; k++) m = fmaxf(m, A[i * 12 + k] + B[k * 12 + j]);
        float sum = 0.f;
        #pragma unroll
        for (int k = 0; k < 12; k++) sum += __expf(A[i * 12 + k] + B[k * 12 + j] - m);
        C[tid] = m + __logf(sum);
    }
}

// K8: chunk products of 16 consecutive M_s (256 blocks)
__global__ void k_crf1(const float* __restrict__ feats, const float* __restrict__ trans,
                       float* __restrict__ chunks) {
    int b = blockIdx.x, tid = threadIdx.x;               // 192 threads, 144 active
    __shared__ float A[144], Bv[144], Tr[144];
    if (tid < 144) Tr[tid] = trans[tid];
    int s0 = b * 16;
    if (tid < 144) A[tid] = trans[tid] + feats[s0 * 12 + (tid % 12)];
    __syncthreads();
    float* cur = A; float* nxt = Bv;
    for (int s = s0 + 1; s < s0 + 16; s++) {
        if (tid < 144) {
            int i = tid / 12, j = tid % 12;
            float m = -1e30f;
            #pragma unroll
            for (int k = 0; k < 12; k++) m = fmaxf(m, cur[i * 12 + k] + Tr[k * 12 + j]);
            float sum = 0.f;
            #pragma unroll
            for (int k = 0; k < 12; k++) sum += __expf(cur[i * 12 + k] + Tr[k * 12 + j] - m);
            nxt[tid] = feats[s * 12 + j] + m + __logf(sum);
        }
        __syncthreads();
        float* tmp = cur; cur = nxt; nxt = tmp;
    }
    if (tid < 144) chunks[b * 144 + tid] = cur[tid];
}

// K9: fold 16 chunks each (16 blocks)
__global__ void k_crf2(const float* __restrict__ chunks, float* __restrict__ lvl2) {
    int b = blockIdx.x, tid = threadIdx.x;               // 192 threads
    __shared__ float A[144], Bv[144], Cc[144];
    if (tid < 144) A[tid] = chunks[(size_t)(b * 16) * 144 + tid];
    __syncthreads();
    for (int m2 = 1; m2 < 16; m2++) {
        if (tid < 144) Bv[tid] = chunks[(size_t)(b * 16 + m2) * 144 + tid];
        __syncthreads();
        lse_merge(A, Bv, Cc, tid);
        __syncthreads();
        if (tid < 144) A[tid] = Cc[tid];
        __syncthreads();
    }
    if (tid < 144) lvl2[b * 144 + tid] = A[tid];
}

// K10: final fold + score (1 block)
__global__ void k_crf3(const float* __restrict__ lvl2, const float* __restrict__ trans,
                       const float* __restrict__ scal, float* __restrict__ out) {
    __shared__ float A[144], Bv[144], Cc[144], alpha[12];
    int tid = threadIdx.x;                               // 192 threads
    if (tid < 144) A[tid] = lvl2[tid];
    __syncthreads();
    for (int m2 = 1; m2 < 16; m2++) {
        if (tid < 144) Bv[tid] = lvl2[m2 * 144 + tid];
        __syncthreads();
        lse_merge(A, Bv, Cc, tid);
        __syncthreads();
        if (tid < 144) A[tid] = Cc[tid];
        __syncthreads();
    }
    if (tid < 12) {
        int j = tid;
        float m = -1e30f;
        #pragma unroll
        for (int i = 0; i < 12; i++) {
            float v = ((i == 10) ? 0.f : -10000.f) + A[i * 12 + j];
            m = fmaxf(m, v);
        }
        float sum = 0.f;
        #pragma unroll
        for (int i = 0; i < 12; i++) {
            float v = ((i == 10) ? 0.f : -10000.f) + A[i * 12 + j];
            sum += __expf(v - m);
        }
        alpha[j] = m + __logf(sum) + trans[j * 12 + 11];
    }
    __syncthreads();
    if (tid == 0) {
        float m = -1e30f;
        #pragma unroll
        for (int j = 0; j < 12; j++) m = fmaxf(m, alpha[j]);
        float sum = 0.f;
        #pragma unroll
        for (int j = 0; j < 12; j++) sum += __expf(alpha[j] - m);
        out[0] = (m + __logf(sum)) - scal[0];
    }
}

// ---------------------------------------------------------------------------
extern "C" void kernel_launch(void* const* d_in, const int* in_sizes, int n_in,
                              void* d_out, int out_size, void* d_ws, size_t ws_size,
                              hipStream_t stream) {
    const int*   sentence = (const int*)d_in[0];
    const int*   chars    = (const int*)d_in[1];
    const int*   tags     = (const int*)d_in[2];
    const float* wemb     = (const float*)d_in[4];
    const float* cemb     = (const float*)d_in[5];
    const float* convw    = (const float*)d_in[6];
    const float* convb    = (const float*)d_in[7];
    const float* wihf     = (const float*)d_in[8];
    const float* whhf     = (const float*)d_in[9];
    const float* bf       = (const float*)d_in[10];
    const float* wihb     = (const float*)d_in[11];
    const float* whhb     = (const float*)d_in[12];
    const float* bb       = (const float*)d_in[13];
    const float* wtag     = (const float*)d_in[14];
    const float* btag     = (const float*)d_in[15];
    const float* trans    = (const float*)d_in[16];

    char* ws = (char*)d_ws;
    float*        embeds = (float*)(ws + WS_EMBEDS);
    float*        gi     = (float*)(ws + WS_GI);
    uint4*        wl     = (uint4*)(ws + WS_WL);
    unsigned int* wv     = (unsigned int*)(ws + WS_WV);
    unsigned int* wa     = (unsigned int*)(ws + WS_WA);
    float*        cfeat  = (float*)(ws + WS_CFEAT);
    float*        hsbuf  = (float*)(ws + WS_HS);
    float*        feats  = (float*)(ws + WS_FEATS);
    float*        chunks = (float*)(ws + WS_CHUNKS);
    float*        lvl2   = (float*)(ws + WS_LVL2);
    float*        scal   = (float*)(ws + WS_SCAL);

    hipFuncSetAttribute((const void*)k_lstm,
                        hipFuncAttributeMaxDynamicSharedMemorySize, LSTM_LDS_BYTES);

    k_pack<<<8, 256, 0, stream>>>(whhf, whhb, wl, wv, wa);
    k_charcnn<<<4096, 128, 0, stream>>>(chars, cemb, convw, convb, cfeat);
    k_embeds<<<4096, 128, 0, stream>>>(sentence, wemb, cfeat, embeds);
    k_gemm<<<dim3(64, 32), 256, 0, stream>>>(embeds, wihf, wihb, bf, bb, gi);
    k_lstm<<<2, 256, LSTM_LDS_BYTES, stream>>>(wl, wv, wa, gi, hsbuf);
    k_feats<<<4096, 192, 0, stream>>>(hsbuf, wtag, btag, feats);
    k_gold<<<1, 256, 0, stream>>>(feats, tags, trans, scal);
    k_crf1<<<256, 192, 0, stream>>>(feats, trans, chunks);
    k_crf2<<<16, 192, 0, stream>>>(chunks, lvl2);
    k_crf3<<<1, 192, 0, stream>>>(lvl2, trans, scal, (float*)d_out);
}